// Round 3
// baseline (3824.059 us; speedup 1.0000x reference)
//
#include <hip/hip_runtime.h>
#include <stdint.h>

// Predictive-coding inference: LAYER_SZS=[1024,4096,4096,4096,1024], B=2048, 5 iters.
// All GEMMs: C[M,N] = A[M,K](bf16) @ W[N,K](bf16)^T, f32 accum, fused epilogues.
// Per iteration: 2 batched GEMM launches (grid.z=3), zero elementwise launches.
//   batch-E: bt_l = d_l @ We_{l-1}^T, epilogue updates a_l in place.
//   batch-P: p_l = a_l @ Wf_l,      epilogue writes t_l=tanh(p_l) and d_l for next iter
//            (l=3 leg: sigmoid -> d3 and final output).

typedef __attribute__((ext_vector_type(8))) __bf16 bf16x8;
typedef __attribute__((ext_vector_type(4))) float f32x4;

#define B_ 2048

__device__ __forceinline__ unsigned short f2bf(float f) {
  union { float f; unsigned u; } v; v.f = f;
  unsigned u = v.u;
  u += 0x7FFFu + ((u >> 16) & 1u);
  return (unsigned short)(u >> 16);
}
__device__ __forceinline__ float bf2f(unsigned short s) {
  union { unsigned u; float f; } v; v.u = ((unsigned)s) << 16;
  return v.f;
}
__device__ __forceinline__ float fast_sig(float x) {
  return 1.0f / (1.0f + __expf(-x));
}
__device__ __forceinline__ float fast_tanh(float x) {
  return 1.0f - 2.0f / (__expf(2.0f * x) + 1.0f);
}

__device__ __forceinline__ void gload_lds16(const void* g, void* l) {
  __builtin_amdgcn_global_load_lds((const __attribute__((address_space(1))) void*)g,
                                   (__attribute__((address_space(3))) void*)l, 16, 0, 0);
}

// epilogue modes
#define M_ACT  0   // t_out=tanh(acc); a_out=relu(t)            (FF g0..g2)
#define M_SIG  1   // s=sig(acc); o0=d3=(targ-s)s(1-s); fout=s  (FF g3, batch-P z2)
#define M_ERR  2   // o0(a) = relu(a + 0.1*acc - 0.1*(a - i0))  (batch-E; i0 = t_{l-1})
#define M_PRED 3   // t=tanh(acc); o0=t; o1=(i0 - t)(1-t^2)     (batch-P z0/z1; i0 = a_{l+1})

struct GDesc {
  const unsigned short* A;   // [M,K] bf16
  const unsigned short* W;   // [N,K] bf16
  unsigned short* o0;
  unsigned short* o1;
  const unsigned short* i0;
  const float* targ;
  float* fout;
  int K;
  int N;                     // C row stride
  int nx;                    // active grid.x (N/128)
  int mode;
};

__global__ __launch_bounds__(256) void gemm_fused(GDesc d0, GDesc d1, GDesc d2) {
  const GDesc d = (blockIdx.z == 0) ? d0 : (blockIdx.z == 1 ? d1 : d2);
  if ((int)blockIdx.x >= d.nx) return;

  __shared__ alignas(16) unsigned short As[128 * 64];
  __shared__ alignas(16) unsigned short Bs[128 * 64];
  const int tid  = threadIdx.x;
  const int wave = tid >> 6, lane = tid & 63;
  const int wrow = wave >> 1, wcol = wave & 1;
  const int row0 = blockIdx.y << 7, col0 = blockIdx.x << 7;
  const int K = d.K, N = d.N;

  f32x4 acc[4][4];
#pragma unroll
  for (int m = 0; m < 4; ++m)
#pragma unroll
    for (int n = 0; n < 4; ++n) acc[m][n] = (f32x4){0.f, 0.f, 0.f, 0.f};

  const int lr = lane >> 3;          // row within 8-row group
  const int lc = (lane & 7) * 8;     // col (shorts; 16B chunk)
  const int nk = K >> 6;             // BK = 64

  for (int kt = 0; kt < nk; ++kt) {
    const int k0 = kt << 6;
#pragma unroll
    for (int i = 0; i < 4; ++i) {
      const int rbase = i * 32 + wave * 8;   // wave-uniform
      gload_lds16(d.A + (size_t)(row0 + rbase + lr) * K + k0 + lc, As + rbase * 64);
      gload_lds16(d.W + (size_t)(col0 + rbase + lr) * K + k0 + lc, Bs + rbase * 64);
    }
    __syncthreads();
#pragma unroll
    for (int kk = 0; kk < 2; ++kk) {
      const int ko = kk * 32 + (lane >> 4) * 8;
      bf16x8 av[4], bv[4];
#pragma unroll
      for (int m = 0; m < 4; ++m)
        av[m] = *(const bf16x8*)(As + (wrow * 64 + m * 16 + (lane & 15)) * 64 + ko);
#pragma unroll
      for (int n = 0; n < 4; ++n)
        bv[n] = *(const bf16x8*)(Bs + (wcol * 64 + n * 16 + (lane & 15)) * 64 + ko);
#pragma unroll
      for (int m = 0; m < 4; ++m)
#pragma unroll
        for (int n = 0; n < 4; ++n)
          acc[m][n] = __builtin_amdgcn_mfma_f32_16x16x32_bf16(av[m], bv[n], acc[m][n], 0, 0, 0);
    }
    __syncthreads();
  }

  // epilogue: D row = (lane>>4)*4 + j, col = lane&15  (m89-verified layout)
  const int rb = row0 + wrow * 64 + ((lane >> 4) << 2);
  const int cb = col0 + wcol * 64 + (lane & 15);
  if (d.mode == M_ACT) {
#pragma unroll
    for (int m = 0; m < 4; ++m)
#pragma unroll
      for (int n = 0; n < 4; ++n)
#pragma unroll
        for (int j = 0; j < 4; ++j) {
          const size_t idx = (size_t)(rb + m * 16 + j) * N + (cb + n * 16);
          float t = fast_tanh(acc[m][n][j]);
          d.o0[idx] = f2bf(t);
          d.o1[idx] = f2bf(fmaxf(t, 0.f));
        }
  } else if (d.mode == M_SIG) {
#pragma unroll
    for (int m = 0; m < 4; ++m)
#pragma unroll
      for (int n = 0; n < 4; ++n)
#pragma unroll
        for (int j = 0; j < 4; ++j) {
          const size_t idx = (size_t)(rb + m * 16 + j) * N + (cb + n * 16);
          float s = fast_sig(acc[m][n][j]);
          d.fout[idx] = s;
          d.o0[idx] = f2bf((d.targ[idx] - s) * s * (1.f - s));
        }
  } else if (d.mode == M_ERR) {
#pragma unroll
    for (int m = 0; m < 4; ++m)
#pragma unroll
      for (int n = 0; n < 4; ++n)
#pragma unroll
        for (int j = 0; j < 4; ++j) {
          const size_t idx = (size_t)(rb + m * 16 + j) * N + (cb + n * 16);
          float av = bf2f(d.o0[idx]);
          float tp = bf2f(d.i0[idx]);
          d.o0[idx] = f2bf(fmaxf(av + 0.1f * acc[m][n][j] - 0.1f * (av - tp), 0.f));
        }
  } else { // M_PRED
#pragma unroll
    for (int m = 0; m < 4; ++m)
#pragma unroll
      for (int n = 0; n < 4; ++n)
#pragma unroll
        for (int j = 0; j < 4; ++j) {
          const size_t idx = (size_t)(rb + m * 16 + j) * N + (cb + n * 16);
          float t = fast_tanh(acc[m][n][j]);
          d.o0[idx] = f2bf(t);
          float an = bf2f(d.i0[idx]);
          d.o1[idx] = f2bf((an - t) * (1.f - t * t));
        }
  }
}

// ---------------- small helper kernels ----------
__global__ void k_cvt(const float* __restrict__ in, unsigned short* __restrict__ out, int n4) {
  int i = blockIdx.x * blockDim.x + threadIdx.x, st = gridDim.x * blockDim.x;
  for (; i < n4; i += st) {
    float4 v = ((const float4*)in)[i];
    ushort4 o; o.x = f2bf(v.x); o.y = f2bf(v.y); o.z = f2bf(v.z); o.w = f2bf(v.w);
    ((ushort4*)out)[i] = o;
  }
}

// d = (a - t) * (1 - t^2), two independent planes via blockIdx.y
__global__ void k_dinit(const unsigned short* __restrict__ t1, const unsigned short* __restrict__ a2,
                        unsigned short* __restrict__ d1,
                        const unsigned short* __restrict__ t2, const unsigned short* __restrict__ a3,
                        unsigned short* __restrict__ d2, int n4) {
  const unsigned short* t = blockIdx.y ? t2 : t1;
  const unsigned short* a = blockIdx.y ? a3 : a2;
  unsigned short* dd = blockIdx.y ? d2 : d1;
  int i = blockIdx.x * blockDim.x + threadIdx.x, st = gridDim.x * blockDim.x;
  for (; i < n4; i += st) {
    ushort4 tv = ((const ushort4*)t)[i];
    ushort4 av = ((const ushort4*)a)[i];
    ushort4 o; float tf;
    tf = bf2f(tv.x); o.x = f2bf((bf2f(av.x) - tf) * (1.f - tf * tf));
    tf = bf2f(tv.y); o.y = f2bf((bf2f(av.y) - tf) * (1.f - tf * tf));
    tf = bf2f(tv.z); o.z = f2bf((bf2f(av.z) - tf) * (1.f - tf * tf));
    tf = bf2f(tv.w); o.w = f2bf((bf2f(av.w) - tf) * (1.f - tf * tf));
    ((ushort4*)dd)[i] = o;
  }
}

// ------------------------------------------------------------------------------------
extern "C" void kernel_launch(void* const* d_in, const int* in_sizes, int n_in,
                              void* d_out, int out_size, void* d_ws, size_t ws_size,
                              hipStream_t stream) {
  (void)in_sizes; (void)n_in; (void)out_size; (void)ws_size;
  const float* x      = (const float*)d_in[0];
  const float* target = (const float*)d_in[1];
  const float* wSrc[7] = {(const float*)d_in[2], (const float*)d_in[3],
                          (const float*)d_in[4], (const float*)d_in[5],
                          (const float*)d_in[6], (const float*)d_in[7],
                          (const float*)d_in[8]};
  const size_t wN[7] = {(size_t)4096 * 1024, (size_t)4096 * 4096, (size_t)4096 * 4096,
                        (size_t)1024 * 4096, (size_t)4096 * 4096, (size_t)4096 * 4096,
                        (size_t)4096 * 1024};

  char* w = (char*)d_ws;
  size_t off = 0;
  auto alloc = [&](size_t bytes) { void* p = w + off; off += bytes; return p; };

  const size_t BIG = (size_t)B_ * 4096;   // 8.4M
  const size_t SML = (size_t)B_ * 1024;   // 2.1M
  unsigned short* xb  = (unsigned short*)alloc(SML * 2);
  unsigned short* a1b = (unsigned short*)alloc(BIG * 2);
  unsigned short* a2b = (unsigned short*)alloc(BIG * 2);
  unsigned short* a3b = (unsigned short*)alloc(BIG * 2);
  unsigned short* t0b = (unsigned short*)alloc(BIG * 2);
  unsigned short* t1b = (unsigned short*)alloc(BIG * 2);
  unsigned short* t2b = (unsigned short*)alloc(BIG * 2);
  unsigned short* d1b = (unsigned short*)alloc(BIG * 2);
  unsigned short* d2b = (unsigned short*)alloc(BIG * 2);
  unsigned short* d3b = (unsigned short*)alloc(SML * 2);
  unsigned short* Wb[7];
  for (int i = 0; i < 7; ++i) Wb[i] = (unsigned short*)alloc(wN[i] * 2);
  // total ~302 MB; round-2 run proved ws_size >= 306 MB.

  const int T = 256;
  auto blocks = [&](int n4) { int b = (n4 + T - 1) / T; return b > 2048 ? 2048 : b; };
  const int n4_big = (int)(BIG >> 2);
  const int n4_sml = (int)(SML >> 2);

  // ---- weight + input conversion ----
  for (int i = 0; i < 7; ++i)
    k_cvt<<<blocks((int)(wN[i] >> 2)), T, 0, stream>>>(wSrc[i], Wb[i], (int)(wN[i] >> 2));
  k_cvt<<<blocks(n4_sml), T, 0, stream>>>(x, xb, n4_sml);

  float* out = (float*)d_out;

  auto desc = [&](const unsigned short* A, const unsigned short* W_, int K, int N, int nx,
                  int mode, unsigned short* o0, unsigned short* o1,
                  const unsigned short* i0, const float* targ, float* fout) {
    GDesc g; g.A = A; g.W = W_; g.o0 = o0; g.o1 = o1; g.i0 = i0;
    g.targ = targ; g.fout = fout; g.K = K; g.N = N; g.nx = nx; g.mode = mode;
    return g;
  };

  // ---- initial feedforward (sequential; grid.z = 1) ----
  {
    GDesc g0 = desc(xb,  Wb[0], 1024, 4096, 32, M_ACT, t0b, a1b, nullptr, nullptr, nullptr);
    gemm_fused<<<dim3(32, 16, 1), 256, 0, stream>>>(g0, g0, g0);
    GDesc g1 = desc(a1b, Wb[1], 4096, 4096, 32, M_ACT, t1b, a2b, nullptr, nullptr, nullptr);
    gemm_fused<<<dim3(32, 16, 1), 256, 0, stream>>>(g1, g1, g1);
    GDesc g2 = desc(a2b, Wb[2], 4096, 4096, 32, M_ACT, t2b, a3b, nullptr, nullptr, nullptr);
    gemm_fused<<<dim3(32, 16, 1), 256, 0, stream>>>(g2, g2, g2);
    GDesc g3 = desc(a3b, Wb[3], 4096, 1024, 8, M_SIG, d3b, nullptr, nullptr, target, out);
    gemm_fused<<<dim3(8, 16, 1), 256, 0, stream>>>(g3, g3, g3);
  }
  // initial deltas d1, d2
  k_dinit<<<dim3(blocks(n4_big), 2), T, 0, stream>>>(t1b, a2b, d1b, t2b, a3b, d2b, n4_big);

  // ---- 5 inference iterations: 2 batched launches each ----
  for (int it = 0; it < 5; ++it) {
    // batch-E: bt_l = d_l @ We_{l-1}^T; a_l = relu(a_l + 0.1*bt - 0.1*(a_l - t_{l-1}))
    GDesc e0 = desc(d1b, Wb[4], 4096, 4096, 32, M_ERR, a1b, nullptr, t0b, nullptr, nullptr);
    GDesc e1 = desc(d2b, Wb[5], 4096, 4096, 32, M_ERR, a2b, nullptr, t1b, nullptr, nullptr);
    GDesc e2 = desc(d3b, Wb[6], 1024, 4096, 32, M_ERR, a3b, nullptr, t2b, nullptr, nullptr);
    gemm_fused<<<dim3(32, 16, 3), 256, 0, stream>>>(e0, e1, e2);
    // batch-P: p_l = a_l @ Wf_l; t_l=tanh, d_l=(a_{l+1}-t)(1-t^2); l=3: sigmoid->d3,out
    GDesc p0 = desc(a1b, Wb[1], 4096, 4096, 32, M_PRED, t1b, d1b, a2b, nullptr, nullptr);
    GDesc p1 = desc(a2b, Wb[2], 4096, 4096, 32, M_PRED, t2b, d2b, a3b, nullptr, nullptr);
    GDesc p2 = desc(a3b, Wb[3], 4096, 1024, 8, M_SIG, d3b, nullptr, nullptr, target, out);
    gemm_fused<<<dim3(32, 16, 3), 256, 0, stream>>>(p0, p1, p2);
  }
}

// Round 4
// 2375.440 us; speedup vs baseline: 1.6098x; 1.6098x over previous
//
#include <hip/hip_runtime.h>
#include <stdint.h>

// Predictive-coding inference: LAYER_SZS=[1024,4096,4096,4096,1024], B=2048, 5 iters.
// GEMM: C[M,N] = A[M,K](bf16) @ W[N,K](bf16)^T, f32 accum, fused epilogues.
// 128x256 tile, BK=64, 8 waves (2x4), 3-deep LDS pipeline with counted vmcnt(6),
// T2 XOR bank-swizzle (pre-swizzled global source + swizzled ds_read, linear
// gload_lds dest), T5 setprio around MFMA clusters. 144KB dynamic LDS, 1 block/CU.

typedef __attribute__((ext_vector_type(8))) __bf16 bf16x8;
typedef __attribute__((ext_vector_type(4))) float f32x4;

#define B_ 2048
#define A_TILE (128 * 64)   // shorts
#define B_TILE (256 * 64)   // shorts
#define LDS_BYTES ((3 * A_TILE + 3 * B_TILE) * 2)   // 147456

__device__ __forceinline__ unsigned short f2bf(float f) {
  union { float f; unsigned u; } v; v.f = f;
  unsigned u = v.u;
  u += 0x7FFFu + ((u >> 16) & 1u);
  return (unsigned short)(u >> 16);
}
__device__ __forceinline__ float bf2f(unsigned short s) {
  union { unsigned u; float f; } v; v.u = ((unsigned)s) << 16;
  return v.f;
}
__device__ __forceinline__ float fast_sig(float x) {
  return 1.0f / (1.0f + __expf(-x));
}
__device__ __forceinline__ float fast_tanh(float x) {
  return 1.0f - 2.0f / (__expf(2.0f * x) + 1.0f);
}

__device__ __forceinline__ void gload_lds16(const void* g, void* l) {
  __builtin_amdgcn_global_load_lds((const __attribute__((address_space(1))) void*)g,
                                   (__attribute__((address_space(3))) void*)l, 16, 0, 0);
}

// epilogue modes
#define M_ACT  0   // t_out=tanh(acc); a_out=relu(t)
#define M_SIG  1   // s=sig(acc); o0=(targ-s)s(1-s); fout=s
#define M_ERR  2   // o0(a) = relu(a + 0.1*acc - 0.1*(a - i0))
#define M_PRED 3   // t=tanh(acc); o0=t; o1=(i0 - t)(1-t^2)

struct GDesc {
  const unsigned short* A;   // [M,K] bf16
  const unsigned short* W;   // [N,K] bf16
  unsigned short* o0;
  unsigned short* o1;
  const unsigned short* i0;
  const float* targ;
  float* fout;
  int K;
  int N;                     // C row stride
  int nx;                    // active grid.x (N/256)
  int mode;
};

__global__ __launch_bounds__(512) void gemm256(GDesc d0, GDesc d1, GDesc d2) {
  const GDesc d = (blockIdx.z == 0) ? d0 : (blockIdx.z == 1 ? d1 : d2);
  if ((int)blockIdx.x >= d.nx) return;

  extern __shared__ unsigned short lds[];
  unsigned short* Ab = lds;                 // [3][128][64]
  unsigned short* Bb = lds + 3 * A_TILE;    // [3][256][64]

  const int tid  = threadIdx.x;
  const int wid  = tid >> 6, lane = tid & 63;
  const int wr   = wid >> 2, wc = wid & 3;         // 2 x 4 waves
  const int row0 = blockIdx.y << 7;                // M base (BM=128)
  const int col0 = blockIdx.x << 8;                // N base (BN=256)
  const int K = d.K, N = d.N;
  const int nt = K >> 6;                           // BK=64 tiles

  // staging coords: thread t covers row (i*64 + t>>3), 16B chunk (t&7), source
  // chunk XOR-swizzled by row&7 so the swizzled ds_read below sees linear data.
  const int sr = tid >> 3;                 // 0..63
  const int sc = tid & 7;                  // chunk
  const unsigned short* Agbase = d.A + (size_t)row0 * K;
  const unsigned short* Bgbase = d.W + (size_t)col0 * K;

  auto stage = [&](int bi, int k0) {
    unsigned short* Al = Ab + bi * A_TILE;
    unsigned short* Bl = Bb + bi * B_TILE;
#pragma unroll
    for (int i = 0; i < 2; ++i) {          // A: 128 rows
      const int r = i * 64 + sr;
      const int cg = (sc ^ (r & 7)) << 3;  // swizzled source col (shorts)
      gload_lds16(Agbase + (size_t)r * K + k0 + cg, Al + (i * 64 + wid * 8) * 64);
    }
#pragma unroll
    for (int i = 0; i < 4; ++i) {          // B: 256 rows
      const int r = i * 64 + sr;
      const int cg = (sc ^ (r & 7)) << 3;
      gload_lds16(Bgbase + (size_t)r * K + k0 + cg, Bl + (i * 64 + wid * 8) * 64);
    }
  };

  f32x4 acc[4][4];
#pragma unroll
  for (int m = 0; m < 4; ++m)
#pragma unroll
    for (int n = 0; n < 4; ++n) acc[m][n] = (f32x4){0.f, 0.f, 0.f, 0.f};

  const int q   = lane >> 4;       // 0..3
  const int j16 = lane & 15;
  const int r3  = j16 & 7;         // row&7 for fragment rows (bases are mult of 16)

  // prologue: stage tiles 0,1; ensure tile 0 landed (newest 6 = tile 1's loads)
  stage(0, 0);
  stage(1, 64);
  asm volatile("s_waitcnt vmcnt(6)" ::: "memory");
  __builtin_amdgcn_s_barrier();

  int bi = 0, si = 2;
  for (int t = 0; t < nt; ++t) {
    if (t + 2 < nt) stage(si, (t + 2) << 6);
    const unsigned short* Ar = Ab + bi * A_TILE;
    const unsigned short* Br = Bb + bi * B_TILE;
#pragma unroll
    for (int ks = 0; ks < 2; ++ks) {
      const int ch = ks * 4 + q;
      bf16x8 av[4], bv[4];
#pragma unroll
      for (int m = 0; m < 4; ++m) {
        const int row = wr * 64 + m * 16 + j16;
        av[m] = *(const bf16x8*)(Ar + row * 64 + ((ch ^ r3) << 3));
      }
#pragma unroll
      for (int n = 0; n < 4; ++n) {
        const int row = wc * 64 + n * 16 + j16;
        bv[n] = *(const bf16x8*)(Br + row * 64 + ((ch ^ r3) << 3));
      }
      __builtin_amdgcn_s_setprio(1);
#pragma unroll
      for (int m = 0; m < 4; ++m)
#pragma unroll
        for (int n = 0; n < 4; ++n)
          acc[m][n] = __builtin_amdgcn_mfma_f32_16x16x32_bf16(av[m], bv[n], acc[m][n], 0, 0, 0);
      __builtin_amdgcn_s_setprio(0);
      if (ks == 0) __builtin_amdgcn_s_barrier();
    }
    if (t + 1 < nt) {
      // gate: tile t+1 must be resident. If tile t+2 was just issued, the newest
      // 6 loads are its; vmcnt(6) => tile t+1 complete. Else drain.
      if (t + 2 < nt) asm volatile("s_waitcnt vmcnt(6)" ::: "memory");
      else            asm volatile("s_waitcnt vmcnt(0)" ::: "memory");
      __builtin_amdgcn_s_barrier();
    }
    bi = (bi == 2) ? 0 : bi + 1;
    si = (si == 2) ? 0 : si + 1;
  }

  // epilogue: D row = (lane>>4)*4 + j, col = lane&15 (m89-verified layout)
  const int rb = row0 + wr * 64 + (q << 2);
  const int cb = col0 + wc * 64 + j16;
  if (d.mode == M_ACT) {
#pragma unroll
    for (int m = 0; m < 4; ++m)
#pragma unroll
      for (int n = 0; n < 4; ++n)
#pragma unroll
        for (int j = 0; j < 4; ++j) {
          const size_t idx = (size_t)(rb + m * 16 + j) * N + (cb + n * 16);
          float t = fast_tanh(acc[m][n][j]);
          d.o0[idx] = f2bf(t);
          d.o1[idx] = f2bf(fmaxf(t, 0.f));
        }
  } else if (d.mode == M_SIG) {
#pragma unroll
    for (int m = 0; m < 4; ++m)
#pragma unroll
      for (int n = 0; n < 4; ++n)
#pragma unroll
        for (int j = 0; j < 4; ++j) {
          const size_t idx = (size_t)(rb + m * 16 + j) * N + (cb + n * 16);
          float s = fast_sig(acc[m][n][j]);
          d.fout[idx] = s;
          d.o0[idx] = f2bf((d.targ[idx] - s) * s * (1.f - s));
        }
  } else if (d.mode == M_ERR) {
#pragma unroll
    for (int m = 0; m < 4; ++m)
#pragma unroll
      for (int n = 0; n < 4; ++n)
#pragma unroll
        for (int j = 0; j < 4; ++j) {
          const size_t idx = (size_t)(rb + m * 16 + j) * N + (cb + n * 16);
          float av = bf2f(d.o0[idx]);
          float tp = bf2f(d.i0[idx]);
          d.o0[idx] = f2bf(fmaxf(av + 0.1f * acc[m][n][j] - 0.1f * (av - tp), 0.f));
        }
  } else { // M_PRED
#pragma unroll
    for (int m = 0; m < 4; ++m)
#pragma unroll
      for (int n = 0; n < 4; ++n)
#pragma unroll
        for (int j = 0; j < 4; ++j) {
          const size_t idx = (size_t)(rb + m * 16 + j) * N + (cb + n * 16);
          float t = fast_tanh(acc[m][n][j]);
          d.o0[idx] = f2bf(t);
          float an = bf2f(d.i0[idx]);
          d.o1[idx] = f2bf((an - t) * (1.f - t * t));
        }
  }
}

// ---------------- small helper kernels ----------
__global__ void k_cvt(const float* __restrict__ in, unsigned short* __restrict__ out, int n4) {
  int i = blockIdx.x * blockDim.x + threadIdx.x, st = gridDim.x * blockDim.x;
  for (; i < n4; i += st) {
    float4 v = ((const float4*)in)[i];
    ushort4 o; o.x = f2bf(v.x); o.y = f2bf(v.y); o.z = f2bf(v.z); o.w = f2bf(v.w);
    ((ushort4*)out)[i] = o;
  }
}

// d = (a - t) * (1 - t^2), two planes via blockIdx.y
__global__ void k_dinit(const unsigned short* __restrict__ t1, const unsigned short* __restrict__ a2,
                        unsigned short* __restrict__ d1,
                        const unsigned short* __restrict__ t2, const unsigned short* __restrict__ a3,
                        unsigned short* __restrict__ d2, int n4) {
  const unsigned short* t = blockIdx.y ? t2 : t1;
  const unsigned short* a = blockIdx.y ? a3 : a2;
  unsigned short* dd = blockIdx.y ? d2 : d1;
  int i = blockIdx.x * blockDim.x + threadIdx.x, st = gridDim.x * blockDim.x;
  for (; i < n4; i += st) {
    ushort4 tv = ((const ushort4*)t)[i];
    ushort4 av = ((const ushort4*)a)[i];
    ushort4 o; float tf;
    tf = bf2f(tv.x); o.x = f2bf((bf2f(av.x) - tf) * (1.f - tf * tf));
    tf = bf2f(tv.y); o.y = f2bf((bf2f(av.y) - tf) * (1.f - tf * tf));
    tf = bf2f(tv.z); o.z = f2bf((bf2f(av.z) - tf) * (1.f - tf * tf));
    tf = bf2f(tv.w); o.w = f2bf((bf2f(av.w) - tf) * (1.f - tf * tf));
    ((ushort4*)dd)[i] = o;
  }
}

// ------------------------------------------------------------------------------------
extern "C" void kernel_launch(void* const* d_in, const int* in_sizes, int n_in,
                              void* d_out, int out_size, void* d_ws, size_t ws_size,
                              hipStream_t stream) {
  (void)in_sizes; (void)n_in; (void)out_size; (void)ws_size;
  const float* x      = (const float*)d_in[0];
  const float* target = (const float*)d_in[1];
  const float* wSrc[7] = {(const float*)d_in[2], (const float*)d_in[3],
                          (const float*)d_in[4], (const float*)d_in[5],
                          (const float*)d_in[6], (const float*)d_in[7],
                          (const float*)d_in[8]};
  const size_t wN[7] = {(size_t)4096 * 1024, (size_t)4096 * 4096, (size_t)4096 * 4096,
                        (size_t)1024 * 4096, (size_t)4096 * 4096, (size_t)4096 * 4096,
                        (size_t)4096 * 1024};

  char* w = (char*)d_ws;
  size_t off = 0;
  auto alloc = [&](size_t bytes) { void* p = w + off; off += bytes; return p; };

  const size_t BIG = (size_t)B_ * 4096;
  const size_t SML = (size_t)B_ * 1024;
  unsigned short* xb  = (unsigned short*)alloc(SML * 2);
  unsigned short* a1b = (unsigned short*)alloc(BIG * 2);
  unsigned short* a2b = (unsigned short*)alloc(BIG * 2);
  unsigned short* a3b = (unsigned short*)alloc(BIG * 2);
  unsigned short* t0b = (unsigned short*)alloc(BIG * 2);
  unsigned short* t1b = (unsigned short*)alloc(BIG * 2);
  unsigned short* t2b = (unsigned short*)alloc(BIG * 2);
  unsigned short* d1b = (unsigned short*)alloc(BIG * 2);
  unsigned short* d2b = (unsigned short*)alloc(BIG * 2);
  unsigned short* d3b = (unsigned short*)alloc(SML * 2);
  unsigned short* Wb[7];
  for (int i = 0; i < 7; ++i) Wb[i] = (unsigned short*)alloc(wN[i] * 2);

  const int T = 256;
  auto blocks = [&](int n4) { int b = (n4 + T - 1) / T; return b > 2048 ? 2048 : b; };
  const int n4_big = (int)(BIG >> 2);
  const int n4_sml = (int)(SML >> 2);

  for (int i = 0; i < 7; ++i)
    k_cvt<<<blocks((int)(wN[i] >> 2)), T, 0, stream>>>(wSrc[i], Wb[i], (int)(wN[i] >> 2));
  k_cvt<<<blocks(n4_sml), T, 0, stream>>>(x, xb, n4_sml);

  float* out = (float*)d_out;

  auto desc = [&](const unsigned short* A, const unsigned short* W_, int K, int N, int nx,
                  int mode, unsigned short* o0, unsigned short* o1,
                  const unsigned short* i0, const float* targ, float* fout) {
    GDesc g; g.A = A; g.W = W_; g.o0 = o0; g.o1 = o1; g.i0 = i0;
    g.targ = targ; g.fout = fout; g.K = K; g.N = N; g.nx = nx; g.mode = mode;
    return g;
  };

  // ---- initial feedforward ----
  {
    GDesc g0 = desc(xb,  Wb[0], 1024, 4096, 16, M_ACT, t0b, a1b, nullptr, nullptr, nullptr);
    gemm256<<<dim3(16, 16, 1), 512, LDS_BYTES, stream>>>(g0, g0, g0);
    GDesc g1 = desc(a1b, Wb[1], 4096, 4096, 16, M_ACT, t1b, a2b, nullptr, nullptr, nullptr);
    gemm256<<<dim3(16, 16, 1), 512, LDS_BYTES, stream>>>(g1, g1, g1);
    GDesc g2 = desc(a2b, Wb[2], 4096, 4096, 16, M_ACT, t2b, a3b, nullptr, nullptr, nullptr);
    gemm256<<<dim3(16, 16, 1), 512, LDS_BYTES, stream>>>(g2, g2, g2);
    GDesc g3 = desc(a3b, Wb[3], 4096, 1024, 4, M_SIG, d3b, nullptr, nullptr, target, out);
    gemm256<<<dim3(4, 16, 1), 512, LDS_BYTES, stream>>>(g3, g3, g3);
  }
  k_dinit<<<dim3(blocks(n4_big), 2), T, 0, stream>>>(t1b, a2b, d1b, t2b, a3b, d2b, n4_big);

  // ---- 5 inference iterations: 2 batched launches each ----
  for (int it = 0; it < 5; ++it) {
    GDesc e0 = desc(d1b, Wb[4], 4096, 4096, 16, M_ERR, a1b, nullptr, t0b, nullptr, nullptr);
    GDesc e1 = desc(d2b, Wb[5], 4096, 4096, 16, M_ERR, a2b, nullptr, t1b, nullptr, nullptr);
    GDesc e2 = desc(d3b, Wb[6], 1024, 4096, 16, M_ERR, a3b, nullptr, t2b, nullptr, nullptr);
    gemm256<<<dim3(16, 16, 3), 512, LDS_BYTES, stream>>>(e0, e1, e2);
    GDesc p0 = desc(a1b, Wb[1], 4096, 4096, 16, M_PRED, t1b, d1b, a2b, nullptr, nullptr);
    GDesc p1 = desc(a2b, Wb[2], 4096, 4096, 16, M_PRED, t2b, d2b, a3b, nullptr, nullptr);
    GDesc p2 = desc(a3b, Wb[3], 4096, 1024, 4, M_SIG, d3b, nullptr, nullptr, target, out);
    gemm256<<<dim3(16, 16, 3), 512, LDS_BYTES, stream>>>(p0, p1, p2);
  }
}